// Round 8
// baseline (1754.046 us; speedup 1.0000x reference)
//
#include <hip/hip_runtime.h>

#define BATCH   8
#define NPTS    8192
#define NPOINT  1024
#define NSAMPLE 32
#define CHANC   32
#define OUTC    35          // 3 xyz + 32 point channels
#define R2      0.0625f     // 0.25^2

typedef float v2f __attribute__((ext_vector_type(2)));

// DPP helpers --------------------------------------------------------------
template <int CTRL>
__device__ __forceinline__ float dpp_max_step(float v) {
    int r = __builtin_amdgcn_update_dpp(__float_as_int(v), __float_as_int(v),
                                        CTRL, 0xf, 0xf, false);
    return fmaxf(v, __int_as_float(r));
}
#define DPP_ROW_SHR(n)  (0x110 | (n))
#define DPP_BCAST15     0x142
#define DPP_BCAST31     0x143

// ---------------------------------------------------------------------------
// Kernel 1: furthest point sampling. One block per batch, 512 threads,
// 16 contiguous points per thread (j = t*16+i). Bit-exact fp32 (contract
// off), packed-f32 distance update.
// Per-iter structure (ONE dependent LDS level — round-7 showed each
// lock-step LDS round-trip costs ~250 cyc):
//   local argmax = fmax tree (depth 4) + parallel eq-mask + ctz  (tie->low i)
//   leader coords = 4-level cndmask tree (overlaps DPP-chain stalls)
//   wave max via DPP; ballot -> lowest lane == lowest index
//   leader writes float4{x,y,z,val}; __syncthreads
//   all lanes: 8 broadcast b128 reads -> fmax tree on .w -> eq-mask + ctz
//   (lowest wave) -> 3-level cndmask coord select. No pts mirror, no idx.
// ---------------------------------------------------------------------------
__global__ __launch_bounds__(512, 1) void fps_kernel(const float* __restrict__ xyz,
                                                     float* __restrict__ new_xyz) {
#pragma clang fp contract(off)
    const int b    = blockIdx.x;
    const int t    = threadIdx.x;
    const int lane = t & 63;
    const int w    = t >> 6;              // wave id, 0..7
    const float* bx = xyz + (size_t)b * NPTS * 3;

    __shared__ __align__(16) float4 part[2][8];   // [parity][wave] {x,y,z,val}

    // thread t owns points j = t*16 + i, i in [0,16): 48 consecutive floats
    v2f px[8], py[8], pz[8], dist[8];
    {
        float f[48];
        float4* fq = (float4*)f;
        const float4* s4 = (const float4*)bx + t * 12;
#pragma unroll
        for (int q = 0; q < 12; ++q) fq[q] = s4[q];
#pragma unroll
        for (int p = 0; p < 8; ++p) {
            px[p] = (v2f){f[6 * p + 0], f[6 * p + 3]};
            py[p] = (v2f){f[6 * p + 1], f[6 * p + 4]};
            pz[p] = (v2f){f[6 * p + 2], f[6 * p + 5]};
            dist[p] = (v2f){1e38f, 1e38f};
        }
    }

    // seed: xyz[b, 0]
    float lx = bx[0], ly = bx[1], lz = bx[2];
    if (t == 0) {
        float* o = new_xyz + (size_t)b * NPOINT * 3;
        o[0] = lx; o[1] = ly; o[2] = lz;
    }

    for (int s = 1; s < NPOINT; ++s) {
        // --- packed update; collect the 16 new dist values ---
        const v2f lx2 = (v2f){lx, lx};
        const v2f ly2 = (v2f){ly, ly};
        const v2f lz2 = (v2f){lz, lz};
        float d[16];
#pragma unroll
        for (int p = 0; p < 8; ++p) {
            const v2f dx = px[p] - lx2;
            const v2f dy = py[p] - ly2;
            const v2f dz = pz[p] - lz2;
            const v2f d2 = (dx * dx + dy * dy) + dz * dz;   // contract off -> exact
            const float d0 = fminf(dist[p].x, d2.x);
            const float d1 = fminf(dist[p].y, d2.y);
            dist[p] = (v2f){d0, d1};
            d[2 * p] = d0; d[2 * p + 1] = d1;
        }

        // --- local argmax: fmax tree (depth 4) + parallel eq-mask + ctz ---
        float m8[8], m4[4], m2[2];
#pragma unroll
        for (int q = 0; q < 8; ++q) m8[q] = fmaxf(d[2 * q], d[2 * q + 1]);
#pragma unroll
        for (int q = 0; q < 4; ++q) m4[q] = fmaxf(m8[2 * q], m8[2 * q + 1]);
        m2[0] = fmaxf(m4[0], m4[1]); m2[1] = fmaxf(m4[2], m4[3]);
        const float bestv = fmaxf(m2[0], m2[1]);
        unsigned lm = 0;
#pragma unroll
        for (int i = 0; i < 16; ++i) lm |= ((unsigned)(d[i] == bestv)) << i;
        const int bi = (int)__builtin_ctz(lm);               // lowest i == lowest index

        // --- leader's coords: 4-level cndmask tree (overlaps DPP latency) ---
        const int g = bi >> 1;
        v2f ax0 = (g & 1) ? px[1] : px[0], ax1 = (g & 1) ? px[3] : px[2];
        v2f ax2 = (g & 1) ? px[5] : px[4], ax3 = (g & 1) ? px[7] : px[6];
        v2f ay0 = (g & 1) ? py[1] : py[0], ay1 = (g & 1) ? py[3] : py[2];
        v2f ay2 = (g & 1) ? py[5] : py[4], ay3 = (g & 1) ? py[7] : py[6];
        v2f az0 = (g & 1) ? pz[1] : pz[0], az1 = (g & 1) ? pz[3] : pz[2];
        v2f az2 = (g & 1) ? pz[5] : pz[4], az3 = (g & 1) ? pz[7] : pz[6];
        v2f bx0 = (g & 2) ? ax1 : ax0, bx1 = (g & 2) ? ax3 : ax2;
        v2f by0 = (g & 2) ? ay1 : ay0, by1 = (g & 2) ? ay3 : ay2;
        v2f bz0 = (g & 2) ? az1 : az0, bz1 = (g & 2) ? az3 : az2;
        const v2f cxv = (g & 4) ? bx1 : bx0;
        const v2f cyv = (g & 4) ? by1 : by0;
        const v2f czv = (g & 4) ? bz1 : bz0;
        const float wx = (bi & 1) ? cxv.y : cxv.x;
        const float wy = (bi & 1) ? cyv.y : cyv.x;
        const float wz = (bi & 1) ? czv.y : czv.x;

        // --- wave64 max via DPP (no LDS) ---
        float v = bestv;
        v = dpp_max_step<DPP_ROW_SHR(1)>(v);
        v = dpp_max_step<DPP_ROW_SHR(2)>(v);
        v = dpp_max_step<DPP_ROW_SHR(4)>(v);
        v = dpp_max_step<DPP_ROW_SHR(8)>(v);
        v = dpp_max_step<DPP_BCAST15>(v);
        v = dpp_max_step<DPP_BCAST31>(v);
        const float smax = __int_as_float(__builtin_amdgcn_readlane(__float_as_int(v), 63));

        // leader lane (lowest lane holding max == lowest index) writes partial
        const unsigned long long m = __ballot(bestv == smax);
        const int par = s & 1;
        if (lane == (int)__builtin_ctzll(m)) {
            part[par][w] = make_float4(wx, wy, wz, smax);
        }
        __syncthreads();

        // --- all lanes: 8 broadcast b128 reads + tree + coord select ---
        const float4* P = part[par];
        const float4 q0 = P[0], q1 = P[1], q2 = P[2], q3 = P[3];
        const float4 q4 = P[4], q5 = P[5], q6 = P[6], q7 = P[7];
        const float M = fmaxf(fmaxf(fmaxf(q0.w, q1.w), fmaxf(q2.w, q3.w)),
                              fmaxf(fmaxf(q4.w, q5.w), fmaxf(q6.w, q7.w)));
        const unsigned mk = (unsigned)(q0.w == M)        | ((unsigned)(q1.w == M) << 1)
                          | ((unsigned)(q2.w == M) << 2) | ((unsigned)(q3.w == M) << 3)
                          | ((unsigned)(q4.w == M) << 4) | ((unsigned)(q5.w == M) << 5)
                          | ((unsigned)(q6.w == M) << 6) | ((unsigned)(q7.w == M) << 7);
        const int slot = (int)__builtin_ctz(mk);   // lowest wave == lowest index
        const float4 a0 = (slot & 1) ? q1 : q0;
        const float4 a1 = (slot & 1) ? q3 : q2;
        const float4 a2 = (slot & 1) ? q5 : q4;
        const float4 a3 = (slot & 1) ? q7 : q6;
        const float4 b0 = (slot & 2) ? a1 : a0;
        const float4 b1 = (slot & 2) ? a3 : a2;
        const float4 cw = (slot & 4) ? b1 : b0;
        lx = cw.x; ly = cw.y; lz = cw.z;
        if (t == 0) {
            float* o = new_xyz + ((size_t)b * NPOINT + s) * 3;
            o[0] = lx; o[1] = ly; o[2] = lz;
        }
    }
}

// ---------------------------------------------------------------------------
// Kernel 2: ball query + grouping. One wave per center (8192 waves).
// x2 unrolled ballot loop (128 points per round, loads hoisted); ordered
// first-NSAMPLE collection, padded with first hit; coalesced 32x35 store.
// ---------------------------------------------------------------------------
__global__ __launch_bounds__(256) void ballgroup_kernel(const float* __restrict__ xyz,
                                                        const float* __restrict__ points,
                                                        const float* __restrict__ new_xyz,
                                                        float* __restrict__ out) {
#pragma clang fp contract(off)
    const int lane = threadIdx.x & 63;
    const int w    = threadIdx.x >> 6;
    const int gw   = blockIdx.x * 4 + w;      // center id, 0..8191
    const int b    = gw >> 10;

    const float* bx  = xyz + (size_t)b * NPTS * 3;
    const float* cen = new_xyz + (size_t)gw * 3;
    const float cx = cen[0], cy = cen[1], cz = cen[2];

    __shared__ int idxbuf[4][NSAMPLE];

    int k = 0;
    for (int base = 0; base < NPTS; base += 128) {
        const int j0 = base + lane;
        const int j1 = j0 + 64;
        const float a0 = bx[j0 * 3 + 0], a1 = bx[j0 * 3 + 1], a2 = bx[j0 * 3 + 2];
        const float c0 = bx[j1 * 3 + 0], c1 = bx[j1 * 3 + 1], c2 = bx[j1 * 3 + 2];
        const float dxa = a0 - cx, dya = a1 - cy, dza = a2 - cz;
        const float d2a = (dxa * dxa + dya * dya) + dza * dza;   // contract off
        const float dxb = c0 - cx, dyb = c1 - cy, dzb = c2 - cz;
        const float d2b = (dxb * dxb + dyb * dyb) + dzb * dzb;
        const bool inA = d2a < R2;
        const bool inB = d2b < R2;

        const unsigned long long mA = __ballot(inA);
        int pre = __popcll(mA & ((1ull << lane) - 1ull));
        if (inA && (k + pre) < NSAMPLE) idxbuf[w][k + pre] = j0;
        k += __popcll(mA);
        if (k >= NSAMPLE) { k = NSAMPLE; break; }        // k is wave-uniform

        const unsigned long long mB = __ballot(inB);
        pre = __popcll(mB & ((1ull << lane) - 1ull));
        if (inB && (k + pre) < NSAMPLE) idxbuf[w][k + pre] = j1;
        k += __popcll(mB);
        if (k >= NSAMPLE) { k = NSAMPLE; break; }
    }
    // center is itself one of the points (d2 == 0), so k >= 1 always.
    const int first = idxbuf[w][0];

    float*       o    = out + (size_t)gw * NSAMPLE * OUTC;
    const float* prow = points + (size_t)b * NPTS * CHANC;
    for (int e = lane; e < NSAMPLE * OUTC; e += 64) {
        const int s = e / OUTC;
        const int c = e - s * OUTC;
        const int j = (s < k) ? idxbuf[w][s] : first;
        float v;
        if (c < 3) {
            const float cc = (c == 0) ? cx : (c == 1) ? cy : cz;
            v = bx[j * 3 + c] - cc;
        } else {
            v = prow[j * CHANC + (c - 3)];
        }
        o[e] = v;   // consecutive lanes -> consecutive addresses (coalesced)
    }
}

// ---------------------------------------------------------------------------
extern "C" void kernel_launch(void* const* d_in, const int* in_sizes, int n_in,
                              void* d_out, int out_size, void* d_ws, size_t ws_size,
                              hipStream_t stream) {
    const float* xyz    = (const float*)d_in[0];   // (8, 8192, 3)  fp32
    const float* points = (const float*)d_in[1];   // (8, 8192, 32) fp32
    float* new_xyz    = (float*)d_out;                         // (8,1024,3)
    float* new_points = new_xyz + (size_t)BATCH * NPOINT * 3;  // (8,1024,32,35)

    fps_kernel<<<BATCH, 512, 0, stream>>>(xyz, new_xyz);
    ballgroup_kernel<<<(BATCH * NPOINT) / 4, 256, 0, stream>>>(xyz, points, new_xyz, new_points);
}

// Round 9
// 1005.770 us; speedup vs baseline: 1.7440x; 1.7440x over previous
//
#include <hip/hip_runtime.h>

#define BATCH   8
#define NPTS    8192
#define NPOINT  1024
#define NSAMPLE 32
#define CHANC   32
#define OUTC    35          // 3 xyz + 32 point channels
#define R2      0.0625f     // 0.25^2

typedef float v2f __attribute__((ext_vector_type(2)));

// DPP helpers --------------------------------------------------------------
template <int CTRL>
__device__ __forceinline__ float dpp_max_step(float v) {
    int r = __builtin_amdgcn_update_dpp(__float_as_int(v), __float_as_int(v),
                                        CTRL, 0xf, 0xf, false);
    return fmaxf(v, __int_as_float(r));
}
#define DPP_ROW_SHR(n)  (0x110 | (n))
#define DPP_BCAST15     0x142
#define DPP_BCAST31     0x143

__device__ __forceinline__ unsigned long long u64max(unsigned long long a,
                                                     unsigned long long b) {
    return a > b ? a : b;
}

// ---------------------------------------------------------------------------
// Kernel 1: furthest point sampling — round-5 structure (proven 903 µs,
// VGPR 88, no spill) + depth-3 tree scan of the 8 u64 partials (was serial
// depth-7). One block per batch, 512 threads, 16 contiguous pts/thread
// (register sweet spot: 32/thread spills — rounds 6 & 8 evidence).
// Bit-exact fp32 (contract off), packed-f32 update, serial inline argmax
// (interleaves with fp math for ILP), DPP wave max + ballot leader, packed
// u64 (val<<32|~idx) partial, one barrier/iter (parity double-buffer),
// winner coords via XOR-swizzled float4 LDS mirror (broadcast b128).
// ---------------------------------------------------------------------------
__global__ __launch_bounds__(512) void fps_kernel(const float* __restrict__ xyz,
                                                  float* __restrict__ new_xyz) {
#pragma clang fp contract(off)
    const int b    = blockIdx.x;
    const int t    = threadIdx.x;
    const int lane = t & 63;
    const int w    = t >> 6;              // wave id, 0..7
    const float* bx = xyz + (size_t)b * NPTS * 3;

    __shared__ float4 pts[NPTS];                    // 128 KB, XOR-swizzled
    __shared__ unsigned long long partial[2][8];

    // thread t owns points j = t*16 + i, i in [0,16): 48 consecutive floats
    v2f px[8], py[8], pz[8], dist[8];
    {
        float f[48];
        float4* fq = (float4*)f;
        const float4* s4 = (const float4*)bx + t * 12;
#pragma unroll
        for (int q = 0; q < 12; ++q) fq[q] = s4[q];
#pragma unroll
        for (int p = 0; p < 8; ++p) {
            px[p] = (v2f){f[6 * p + 0], f[6 * p + 3]};
            py[p] = (v2f){f[6 * p + 1], f[6 * p + 4]};
            pz[p] = (v2f){f[6 * p + 2], f[6 * p + 5]};
            dist[p] = (v2f){1e38f, 1e38f};
        }
#pragma unroll
        for (int i = 0; i < 16; ++i) {
            const int j  = t * 16 + i;
            const int js = j ^ ((j >> 4) & 7);      // bank swizzle
            pts[js] = make_float4(f[3 * i + 0], f[3 * i + 1], f[3 * i + 2], 0.0f);
        }
    }
    __syncthreads();

    // seed: xyz[b, 0]  (swizzle(0) == 0)
    float4 c0 = pts[0];
    float lx = c0.x, ly = c0.y, lz = c0.z;
    if (t == 0) {
        float* o = new_xyz + (size_t)b * NPOINT * 3;
        o[0] = lx; o[1] = ly; o[2] = lz;
    }

    for (int s = 1; s < NPOINT; ++s) {
        // --- packed update + serial inline argmax over 16 points ---
        const v2f lx2 = (v2f){lx, lx};
        const v2f ly2 = (v2f){ly, ly};
        const v2f lz2 = (v2f){lz, lz};
        float bestv = -1.0f;
        int   bi    = 0;
#pragma unroll
        for (int p = 0; p < 8; ++p) {
            const v2f dx = px[p] - lx2;
            const v2f dy = py[p] - ly2;
            const v2f dz = pz[p] - lz2;
            const v2f d2 = (dx * dx + dy * dy) + dz * dz;   // contract off -> exact
            const float d0 = fminf(dist[p].x, d2.x);
            const float d1 = fminf(dist[p].y, d2.y);
            dist[p] = (v2f){d0, d1};
            if (d0 > bestv) { bestv = d0; bi = 2 * p; }     // strict > keeps lowest i
            if (d1 > bestv) { bestv = d1; bi = 2 * p + 1; }
        }
        const int besti = (t << 4) + bi;

        // --- wave64 max via DPP (no LDS) ---
        float v = bestv;
        v = dpp_max_step<DPP_ROW_SHR(1)>(v);
        v = dpp_max_step<DPP_ROW_SHR(2)>(v);
        v = dpp_max_step<DPP_ROW_SHR(4)>(v);
        v = dpp_max_step<DPP_ROW_SHR(8)>(v);
        v = dpp_max_step<DPP_BCAST15>(v);
        v = dpp_max_step<DPP_BCAST31>(v);
        const float smax = __int_as_float(__builtin_amdgcn_readlane(__float_as_int(v), 63));

        // leader lane (lowest lane holding the max == lowest index) writes partial
        const unsigned long long m = __ballot(bestv == smax);
        const int par = s & 1;
        if (lane == (int)__builtin_ctzll(m)) {
            partial[par][w] = ((unsigned long long)__float_as_uint(smax) << 32)
                              | (unsigned)(~besti);
        }
        __syncthreads();

        // --- all lanes scan the 8 partials: depth-3 u64 max tree ---
        const unsigned long long* P = partial[par];
        const unsigned long long a0 = P[0], a1 = P[1], a2 = P[2], a3 = P[3];
        const unsigned long long a4 = P[4], a5 = P[5], a6 = P[6], a7 = P[7];
        const unsigned long long bp =
            u64max(u64max(u64max(a0, a1), u64max(a2, a3)),
                   u64max(u64max(a4, a5), u64max(a6, a7)));
        const int idx = (int)(~(unsigned)bp);
        const int js  = idx ^ ((idx >> 4) & 7);
        const float4 cw = pts[js];              // uniform -> broadcast b128
        lx = cw.x; ly = cw.y; lz = cw.z;
        if (t == 0) {
            float* o = new_xyz + ((size_t)b * NPOINT + s) * 3;
            o[0] = lx; o[1] = ly; o[2] = lz;
        }
    }
}

// ---------------------------------------------------------------------------
// Kernel 2: ball query + grouping. One wave per center (8192 waves).
// x2 unrolled ballot loop (128 points per round, loads hoisted); ordered
// first-NSAMPLE collection, padded with first hit; coalesced 32x35 store.
// ---------------------------------------------------------------------------
__global__ __launch_bounds__(256) void ballgroup_kernel(const float* __restrict__ xyz,
                                                        const float* __restrict__ points,
                                                        const float* __restrict__ new_xyz,
                                                        float* __restrict__ out) {
#pragma clang fp contract(off)
    const int lane = threadIdx.x & 63;
    const int w    = threadIdx.x >> 6;
    const int gw   = blockIdx.x * 4 + w;      // center id, 0..8191
    const int b    = gw >> 10;

    const float* bx  = xyz + (size_t)b * NPTS * 3;
    const float* cen = new_xyz + (size_t)gw * 3;
    const float cx = cen[0], cy = cen[1], cz = cen[2];

    __shared__ int idxbuf[4][NSAMPLE];

    int k = 0;
    for (int base = 0; base < NPTS; base += 128) {
        const int j0 = base + lane;
        const int j1 = j0 + 64;
        const float a0 = bx[j0 * 3 + 0], a1 = bx[j0 * 3 + 1], a2 = bx[j0 * 3 + 2];
        const float c0 = bx[j1 * 3 + 0], c1 = bx[j1 * 3 + 1], c2 = bx[j1 * 3 + 2];
        const float dxa = a0 - cx, dya = a1 - cy, dza = a2 - cz;
        const float d2a = (dxa * dxa + dya * dya) + dza * dza;   // contract off
        const float dxb = c0 - cx, dyb = c1 - cy, dzb = c2 - cz;
        const float d2b = (dxb * dxb + dyb * dyb) + dzb * dzb;
        const bool inA = d2a < R2;
        const bool inB = d2b < R2;

        const unsigned long long mA = __ballot(inA);
        int pre = __popcll(mA & ((1ull << lane) - 1ull));
        if (inA && (k + pre) < NSAMPLE) idxbuf[w][k + pre] = j0;
        k += __popcll(mA);
        if (k >= NSAMPLE) { k = NSAMPLE; break; }        // k is wave-uniform

        const unsigned long long mB = __ballot(inB);
        pre = __popcll(mB & ((1ull << lane) - 1ull));
        if (inB && (k + pre) < NSAMPLE) idxbuf[w][k + pre] = j1;
        k += __popcll(mB);
        if (k >= NSAMPLE) { k = NSAMPLE; break; }
    }
    // center is itself one of the points (d2 == 0), so k >= 1 always.
    const int first = idxbuf[w][0];

    float*       o    = out + (size_t)gw * NSAMPLE * OUTC;
    const float* prow = points + (size_t)b * NPTS * CHANC;
    for (int e = lane; e < NSAMPLE * OUTC; e += 64) {
        const int s = e / OUTC;
        const int c = e - s * OUTC;
        const int j = (s < k) ? idxbuf[w][s] : first;
        float v;
        if (c < 3) {
            const float cc = (c == 0) ? cx : (c == 1) ? cy : cz;
            v = bx[j * 3 + c] - cc;
        } else {
            v = prow[j * CHANC + (c - 3)];
        }
        o[e] = v;   // consecutive lanes -> consecutive addresses (coalesced)
    }
}

// ---------------------------------------------------------------------------
extern "C" void kernel_launch(void* const* d_in, const int* in_sizes, int n_in,
                              void* d_out, int out_size, void* d_ws, size_t ws_size,
                              hipStream_t stream) {
    const float* xyz    = (const float*)d_in[0];   // (8, 8192, 3)  fp32
    const float* points = (const float*)d_in[1];   // (8, 8192, 32) fp32
    float* new_xyz    = (float*)d_out;                         // (8,1024,3)
    float* new_points = new_xyz + (size_t)BATCH * NPOINT * 3;  // (8,1024,32,35)

    fps_kernel<<<BATCH, 512, 0, stream>>>(xyz, new_xyz);
    ballgroup_kernel<<<(BATCH * NPOINT) / 4, 256, 0, stream>>>(xyz, points, new_xyz, new_points);
}

// Round 10
// 1005.295 us; speedup vs baseline: 1.7448x; 1.0005x over previous
//
#include <hip/hip_runtime.h>

#define BATCH   8
#define NPTS    8192
#define NPOINT  1024
#define NSAMPLE 32
#define CHANC   32
#define OUTC    35          // 3 xyz + 32 point channels
#define R2      0.0625f     // 0.25^2

typedef float v2f __attribute__((ext_vector_type(2)));

// DPP helpers --------------------------------------------------------------
template <int CTRL>
__device__ __forceinline__ float dpp_max_step(float v) {
    int r = __builtin_amdgcn_update_dpp(__float_as_int(v), __float_as_int(v),
                                        CTRL, 0xf, 0xf, false);
    return fmaxf(v, __int_as_float(r));
}
#define DPP_ROW_SHR(n)  (0x110 | (n))
#define DPP_BCAST15     0x142
#define DPP_BCAST31     0x143

__device__ __forceinline__ unsigned long long u64max(unsigned long long a,
                                                     unsigned long long b) {
    return a > b ? a : b;
}

// ---------------------------------------------------------------------------
// Kernel 1: furthest point sampling — FROZEN round-9 structure (898 µs,
// VGPR 88, no spill; structural floor for 1-CU-per-batch: ~1450 cyc issue +
// ~650 cyc barrier/LDS-chain per iteration; restructures spill (r6/r8) or
// add LDS levels (r7)). One block per batch, 512 threads, 16 contiguous
// pts/thread. Bit-exact fp32 (contract off), packed-f32 update, serial
// inline argmax, DPP wave max + ballot leader, packed u64 (val<<32|~idx)
// partial, one barrier/iter (parity double-buffer), depth-3 u64 tree scan,
// winner coords via XOR-swizzled float4 LDS mirror (broadcast b128).
// ---------------------------------------------------------------------------
__global__ __launch_bounds__(512) void fps_kernel(const float* __restrict__ xyz,
                                                  float* __restrict__ new_xyz) {
#pragma clang fp contract(off)
    const int b    = blockIdx.x;
    const int t    = threadIdx.x;
    const int lane = t & 63;
    const int w    = t >> 6;              // wave id, 0..7
    const float* bx = xyz + (size_t)b * NPTS * 3;

    __shared__ float4 pts[NPTS];                    // 128 KB, XOR-swizzled
    __shared__ unsigned long long partial[2][8];

    // thread t owns points j = t*16 + i, i in [0,16): 48 consecutive floats
    v2f px[8], py[8], pz[8], dist[8];
    {
        float f[48];
        float4* fq = (float4*)f;
        const float4* s4 = (const float4*)bx + t * 12;
#pragma unroll
        for (int q = 0; q < 12; ++q) fq[q] = s4[q];
#pragma unroll
        for (int p = 0; p < 8; ++p) {
            px[p] = (v2f){f[6 * p + 0], f[6 * p + 3]};
            py[p] = (v2f){f[6 * p + 1], f[6 * p + 4]};
            pz[p] = (v2f){f[6 * p + 2], f[6 * p + 5]};
            dist[p] = (v2f){1e38f, 1e38f};
        }
#pragma unroll
        for (int i = 0; i < 16; ++i) {
            const int j  = t * 16 + i;
            const int js = j ^ ((j >> 4) & 7);      // bank swizzle
            pts[js] = make_float4(f[3 * i + 0], f[3 * i + 1], f[3 * i + 2], 0.0f);
        }
    }
    __syncthreads();

    // seed: xyz[b, 0]  (swizzle(0) == 0)
    float4 c0 = pts[0];
    float lx = c0.x, ly = c0.y, lz = c0.z;
    if (t == 0) {
        float* o = new_xyz + (size_t)b * NPOINT * 3;
        o[0] = lx; o[1] = ly; o[2] = lz;
    }

    for (int s = 1; s < NPOINT; ++s) {
        // --- packed update + serial inline argmax over 16 points ---
        const v2f lx2 = (v2f){lx, lx};
        const v2f ly2 = (v2f){ly, ly};
        const v2f lz2 = (v2f){lz, lz};
        float bestv = -1.0f;
        int   bi    = 0;
#pragma unroll
        for (int p = 0; p < 8; ++p) {
            const v2f dx = px[p] - lx2;
            const v2f dy = py[p] - ly2;
            const v2f dz = pz[p] - lz2;
            const v2f d2 = (dx * dx + dy * dy) + dz * dz;   // contract off -> exact
            const float d0 = fminf(dist[p].x, d2.x);
            const float d1 = fminf(dist[p].y, d2.y);
            dist[p] = (v2f){d0, d1};
            if (d0 > bestv) { bestv = d0; bi = 2 * p; }     // strict > keeps lowest i
            if (d1 > bestv) { bestv = d1; bi = 2 * p + 1; }
        }
        const int besti = (t << 4) + bi;

        // --- wave64 max via DPP (no LDS) ---
        float v = bestv;
        v = dpp_max_step<DPP_ROW_SHR(1)>(v);
        v = dpp_max_step<DPP_ROW_SHR(2)>(v);
        v = dpp_max_step<DPP_ROW_SHR(4)>(v);
        v = dpp_max_step<DPP_ROW_SHR(8)>(v);
        v = dpp_max_step<DPP_BCAST15>(v);
        v = dpp_max_step<DPP_BCAST31>(v);
        const float smax = __int_as_float(__builtin_amdgcn_readlane(__float_as_int(v), 63));

        // leader lane (lowest lane holding the max == lowest index) writes partial
        const unsigned long long m = __ballot(bestv == smax);
        const int par = s & 1;
        if (lane == (int)__builtin_ctzll(m)) {
            partial[par][w] = ((unsigned long long)__float_as_uint(smax) << 32)
                              | (unsigned)(~besti);
        }
        __syncthreads();

        // --- all lanes scan the 8 partials: depth-3 u64 max tree ---
        const unsigned long long* P = partial[par];
        const unsigned long long a0 = P[0], a1 = P[1], a2 = P[2], a3 = P[3];
        const unsigned long long a4 = P[4], a5 = P[5], a6 = P[6], a7 = P[7];
        const unsigned long long bp =
            u64max(u64max(u64max(a0, a1), u64max(a2, a3)),
                   u64max(u64max(a4, a5), u64max(a6, a7)));
        const int idx = (int)(~(unsigned)bp);
        const int js  = idx ^ ((idx >> 4) & 7);
        const float4 cw = pts[js];              // uniform -> broadcast b128
        lx = cw.x; ly = cw.y; lz = cw.z;
        if (t == 0) {
            float* o = new_xyz + ((size_t)b * NPOINT + s) * 3;
            o[0] = lx; o[1] = ly; o[2] = lz;
        }
    }
}

// ---------------------------------------------------------------------------
// Kernel 2: ball query + grouping. ONE BLOCK (4 waves) PER CENTER:
// wave r scans index-quarter [r*2048, (r+1)*2048) — 4x lower scan latency,
// same total work. Each quarter collects its first <=32 in-radius indices
// (ballot-ordered ascending); one barrier; prefix-merge of the 4 counts
// reconstructs "first NSAMPLE ascending, pad with first hit" exactly
// (quarters are index-ordered). __any-skip avoids ballot bookkeeping on
// hit-free rounds (common: FPS centers sit in low-density regions).
// Gather phase: 256 threads over 32x35 elems, coalesced stores.
// ---------------------------------------------------------------------------
__global__ __launch_bounds__(256) void ballgroup_kernel(const float* __restrict__ xyz,
                                                        const float* __restrict__ points,
                                                        const float* __restrict__ new_xyz,
                                                        float* __restrict__ out) {
#pragma clang fp contract(off)
    const int tid  = threadIdx.x;
    const int lane = tid & 63;
    const int r    = tid >> 6;            // wave id = quarter id, 0..3
    const int gw   = blockIdx.x;          // center id, 0..8191
    const int b    = gw >> 10;

    const float* bx  = xyz + (size_t)b * NPTS * 3;
    const float* cen = new_xyz + (size_t)gw * 3;
    const float cx = cen[0], cy = cen[1], cz = cen[2];

    __shared__ int qidx[4][NSAMPLE];
    __shared__ int qcnt[4];

    // --- scan this wave's quarter: 2048 pts, 16 x2-unrolled rounds ---
    int k = 0;
    const int qbase = r << 11;
    for (int base = qbase; base < qbase + 2048; base += 128) {
        const int j0 = base + lane;
        const int j1 = j0 + 64;
        const float a0 = bx[j0 * 3 + 0], a1 = bx[j0 * 3 + 1], a2 = bx[j0 * 3 + 2];
        const float c0 = bx[j1 * 3 + 0], c1 = bx[j1 * 3 + 1], c2 = bx[j1 * 3 + 2];
        const float dxa = a0 - cx, dya = a1 - cy, dza = a2 - cz;
        const float d2a = (dxa * dxa + dya * dya) + dza * dza;   // contract off
        const float dxb = c0 - cx, dyb = c1 - cy, dzb = c2 - cz;
        const float d2b = (dxb * dxb + dyb * dyb) + dzb * dzb;
        const bool inA = d2a < R2;
        const bool inB = d2b < R2;

        if (__any(inA || inB)) {          // skip bookkeeping on empty rounds
            const unsigned long long mA = __ballot(inA);
            int pre = __popcll(mA & ((1ull << lane) - 1ull));
            if (inA && (k + pre) < NSAMPLE) qidx[r][k + pre] = j0;
            k += __popcll(mA);
            if (k >= NSAMPLE) { k = NSAMPLE; break; }     // k is wave-uniform

            const unsigned long long mB = __ballot(inB);
            pre = __popcll(mB & ((1ull << lane) - 1ull));
            if (inB && (k + pre) < NSAMPLE) qidx[r][k + pre] = j1;
            k += __popcll(mB);
            if (k >= NSAMPLE) { k = NSAMPLE; break; }
        }
    }
    if (lane == 0) qcnt[r] = k;
    __syncthreads();

    // --- prefix-merge: first NSAMPLE of the concatenated quarters ---
    const int c0n = qcnt[0], c1n = qcnt[1], c2n = qcnt[2], c3n = qcnt[3];
    const int o1 = c0n, o2 = c0n + c1n, o3 = o2 + c2n;
    const int total = o3 + c3n;
    const int kk = total < NSAMPLE ? total : NSAMPLE;
    // first hit overall = first entry of the first nonempty quarter
    // (center's own point has d2==0, so total >= 1 always)
    const int r0 = (c0n > 0) ? 0 : (c1n > 0) ? 1 : (c2n > 0) ? 2 : 3;
    const int firstIdx = qidx[r0][0];

    // --- gather: 32x35 output elems across 256 threads, coalesced ---
    float*       o    = out + (size_t)gw * NSAMPLE * OUTC;
    const float* prow = points + (size_t)b * NPTS * CHANC;
    for (int e = tid; e < NSAMPLE * OUTC; e += 256) {
        const int s = e / OUTC;
        const int c = e - s * OUTC;
        int j;
        if (s < kk) {
            const int rr  = (int)(s >= o1) + (int)(s >= o2) + (int)(s >= o3);
            const int off = (rr == 0) ? 0 : (rr == 1) ? o1 : (rr == 2) ? o2 : o3;
            j = qidx[rr][s - off];
        } else {
            j = firstIdx;
        }
        float v;
        if (c < 3) {
            const float cc = (c == 0) ? cx : (c == 1) ? cy : cz;
            v = bx[j * 3 + c] - cc;
        } else {
            v = prow[j * CHANC + (c - 3)];
        }
        o[e] = v;   // consecutive lanes -> consecutive addresses (coalesced)
    }
}

// ---------------------------------------------------------------------------
extern "C" void kernel_launch(void* const* d_in, const int* in_sizes, int n_in,
                              void* d_out, int out_size, void* d_ws, size_t ws_size,
                              hipStream_t stream) {
    const float* xyz    = (const float*)d_in[0];   // (8, 8192, 3)  fp32
    const float* points = (const float*)d_in[1];   // (8, 8192, 32) fp32
    float* new_xyz    = (float*)d_out;                         // (8,1024,3)
    float* new_points = new_xyz + (size_t)BATCH * NPOINT * 3;  // (8,1024,32,35)

    fps_kernel<<<BATCH, 512, 0, stream>>>(xyz, new_xyz);
    ballgroup_kernel<<<BATCH * NPOINT, 256, 0, stream>>>(xyz, points, new_xyz, new_points);
}

// Round 11
// 1000.981 us; speedup vs baseline: 1.7523x; 1.0043x over previous
//
#include <hip/hip_runtime.h>

#define BATCH   8
#define NPTS    8192
#define NPOINT  1024
#define NSAMPLE 32
#define CHANC   32
#define OUTC    35          // 3 xyz + 32 point channels
#define R2      0.0625f     // 0.25^2

typedef float v2f __attribute__((ext_vector_type(2)));

// DPP helpers --------------------------------------------------------------
template <int CTRL>
__device__ __forceinline__ float dpp_max_step(float v) {
    int r = __builtin_amdgcn_update_dpp(__float_as_int(v), __float_as_int(v),
                                        CTRL, 0xf, 0xf, false);
    return fmaxf(v, __int_as_float(r));
}
#define DPP_ROW_SHR(n)  (0x110 | (n))
#define DPP_BCAST15     0x142
#define DPP_BCAST31     0x143

__device__ __forceinline__ unsigned long long u64max(unsigned long long a,
                                                     unsigned long long b) {
    return a > b ? a : b;
}

// ---------------------------------------------------------------------------
// Kernel 1: furthest point sampling — FROZEN round-9 structure (898 µs,
// VGPR 88, no spill; structural floor for 1-CU-per-batch: restructures
// spill (r6/r8) or add ~250-cyc LDS levels (r7)). One block per batch,
// 512 threads, 16 contiguous pts/thread. Bit-exact fp32 (contract off),
// packed-f32 update, serial inline argmax, DPP wave max + ballot leader,
// packed u64 (val<<32|~idx) partial, one barrier/iter (parity dbuf),
// depth-3 u64 tree scan, coords via XOR-swizzled float4 LDS mirror.
// ---------------------------------------------------------------------------
__global__ __launch_bounds__(512) void fps_kernel(const float* __restrict__ xyz,
                                                  float* __restrict__ new_xyz) {
#pragma clang fp contract(off)
    const int b    = blockIdx.x;
    const int t    = threadIdx.x;
    const int lane = t & 63;
    const int w    = t >> 6;              // wave id, 0..7
    const float* bx = xyz + (size_t)b * NPTS * 3;

    __shared__ float4 pts[NPTS];                    // 128 KB, XOR-swizzled
    __shared__ unsigned long long partial[2][8];

    // thread t owns points j = t*16 + i, i in [0,16): 48 consecutive floats
    v2f px[8], py[8], pz[8], dist[8];
    {
        float f[48];
        float4* fq = (float4*)f;
        const float4* s4 = (const float4*)bx + t * 12;
#pragma unroll
        for (int q = 0; q < 12; ++q) fq[q] = s4[q];
#pragma unroll
        for (int p = 0; p < 8; ++p) {
            px[p] = (v2f){f[6 * p + 0], f[6 * p + 3]};
            py[p] = (v2f){f[6 * p + 1], f[6 * p + 4]};
            pz[p] = (v2f){f[6 * p + 2], f[6 * p + 5]};
            dist[p] = (v2f){1e38f, 1e38f};
        }
#pragma unroll
        for (int i = 0; i < 16; ++i) {
            const int j  = t * 16 + i;
            const int js = j ^ ((j >> 4) & 7);      // bank swizzle
            pts[js] = make_float4(f[3 * i + 0], f[3 * i + 1], f[3 * i + 2], 0.0f);
        }
    }
    __syncthreads();

    // seed: xyz[b, 0]  (swizzle(0) == 0)
    float4 c0 = pts[0];
    float lx = c0.x, ly = c0.y, lz = c0.z;
    if (t == 0) {
        float* o = new_xyz + (size_t)b * NPOINT * 3;
        o[0] = lx; o[1] = ly; o[2] = lz;
    }

    for (int s = 1; s < NPOINT; ++s) {
        // --- packed update + serial inline argmax over 16 points ---
        const v2f lx2 = (v2f){lx, lx};
        const v2f ly2 = (v2f){ly, ly};
        const v2f lz2 = (v2f){lz, lz};
        float bestv = -1.0f;
        int   bi    = 0;
#pragma unroll
        for (int p = 0; p < 8; ++p) {
            const v2f dx = px[p] - lx2;
            const v2f dy = py[p] - ly2;
            const v2f dz = pz[p] - lz2;
            const v2f d2 = (dx * dx + dy * dy) + dz * dz;   // contract off -> exact
            const float d0 = fminf(dist[p].x, d2.x);
            const float d1 = fminf(dist[p].y, d2.y);
            dist[p] = (v2f){d0, d1};
            if (d0 > bestv) { bestv = d0; bi = 2 * p; }     // strict > keeps lowest i
            if (d1 > bestv) { bestv = d1; bi = 2 * p + 1; }
        }
        const int besti = (t << 4) + bi;

        // --- wave64 max via DPP (no LDS) ---
        float v = bestv;
        v = dpp_max_step<DPP_ROW_SHR(1)>(v);
        v = dpp_max_step<DPP_ROW_SHR(2)>(v);
        v = dpp_max_step<DPP_ROW_SHR(4)>(v);
        v = dpp_max_step<DPP_ROW_SHR(8)>(v);
        v = dpp_max_step<DPP_BCAST15>(v);
        v = dpp_max_step<DPP_BCAST31>(v);
        const float smax = __int_as_float(__builtin_amdgcn_readlane(__float_as_int(v), 63));

        // leader lane (lowest lane holding the max == lowest index) writes partial
        const unsigned long long m = __ballot(bestv == smax);
        const int par = s & 1;
        if (lane == (int)__builtin_ctzll(m)) {
            partial[par][w] = ((unsigned long long)__float_as_uint(smax) << 32)
                              | (unsigned)(~besti);
        }
        __syncthreads();

        // --- all lanes scan the 8 partials: depth-3 u64 max tree ---
        const unsigned long long* P = partial[par];
        const unsigned long long a0 = P[0], a1 = P[1], a2 = P[2], a3 = P[3];
        const unsigned long long a4 = P[4], a5 = P[5], a6 = P[6], a7 = P[7];
        const unsigned long long bp =
            u64max(u64max(u64max(a0, a1), u64max(a2, a3)),
                   u64max(u64max(a4, a5), u64max(a6, a7)));
        const int idx = (int)(~(unsigned)bp);
        const int js  = idx ^ ((idx >> 4) & 7);
        const float4 cw = pts[js];              // uniform -> broadcast b128
        lx = cw.x; ly = cw.y; lz = cw.z;
        if (t == 0) {
            float* o = new_xyz + ((size_t)b * NPOINT + s) * 3;
            o[0] = lx; o[1] = ly; o[2] = lz;
        }
    }
}

// ---------------------------------------------------------------------------
// Kernel 2: ball query + grouping. One block (4 waves) per center; wave r
// owns index-quarter r. SCAN IS SUPERROUND-PIPELINED: 256 pts per superround
// — all 12 loads hoisted & independent (deep pipeline), THEN 4 ballot masks,
// THEN serial k-bookkeeping (VALU-only), ONE early-exit check per superround
// (round-10 lesson: per-round break serializes loads on the ballot chain).
// Quarter results merged by prefix (exact "first 32 ascending, pad w/ first
// hit": each quarter stores its earliest <=32 hits, so the merged 32-prefix
// is always available). Gather: 256 threads over 32x35, coalesced stores.
// ---------------------------------------------------------------------------
__global__ __launch_bounds__(256) void ballgroup_kernel(const float* __restrict__ xyz,
                                                        const float* __restrict__ points,
                                                        const float* __restrict__ new_xyz,
                                                        float* __restrict__ out) {
#pragma clang fp contract(off)
    const int tid  = threadIdx.x;
    const int lane = tid & 63;
    const int r    = tid >> 6;            // wave id = quarter id, 0..3
    const int gw   = blockIdx.x;          // center id, 0..8191
    const int b    = gw >> 10;

    const float* bx  = xyz + (size_t)b * NPTS * 3;
    const float* cen = new_xyz + (size_t)gw * 3;
    const float cx = cen[0], cy = cen[1], cz = cen[2];

    __shared__ int qidx[4][NSAMPLE];
    __shared__ int qcnt[4];

    // --- scan this wave's quarter: 2048 pts, 8 superrounds of 256 ---
    int k = 0;
    const int qbase = r << 11;
    for (int base = qbase; base < qbase + 2048; base += 256) {
        // phase 1: hoist all 12 loads (independent -> deep pipeline)
        float xs[4], ys[4], zs[4];
#pragma unroll
        for (int u = 0; u < 4; ++u) {
            const int j = base + u * 64 + lane;
            xs[u] = bx[j * 3 + 0];
            ys[u] = bx[j * 3 + 1];
            zs[u] = bx[j * 3 + 2];
        }
        // phase 2: distances + masks (no memory)
        bool in[4];
#pragma unroll
        for (int u = 0; u < 4; ++u) {
            const float dx = xs[u] - cx;
            const float dy = ys[u] - cy;
            const float dz = zs[u] - cz;
            const float d2 = (dx * dx + dy * dy) + dz * dz;   // contract off
            in[u] = d2 < R2;
        }
        // phase 3: serial bookkeeping (VALU/LDS only, no loads on chain)
#pragma unroll
        for (int u = 0; u < 4; ++u) {
            const unsigned long long mu = __ballot(in[u]);
            const int pre = __popcll(mu & ((1ull << lane) - 1ull));
            if (in[u] && (k + pre) < NSAMPLE) qidx[r][k + pre] = base + u * 64 + lane;
            k += __popcll(mu);
        }
        if (k >= NSAMPLE) break;          // one exit check per superround
    }
    if (k > NSAMPLE) k = NSAMPLE;
    if (lane == 0) qcnt[r] = k;
    __syncthreads();

    // --- prefix-merge: first NSAMPLE of the concatenated quarters ---
    const int c0n = qcnt[0], c1n = qcnt[1], c2n = qcnt[2], c3n = qcnt[3];
    const int o1 = c0n, o2 = c0n + c1n, o3 = o2 + c2n;
    const int total = o3 + c3n;
    const int kk = total < NSAMPLE ? total : NSAMPLE;
    // first hit overall = first entry of the first nonempty quarter
    // (center's own point has d2==0, so total >= 1 always)
    const int r0 = (c0n > 0) ? 0 : (c1n > 0) ? 1 : (c2n > 0) ? 2 : 3;
    const int firstIdx = qidx[r0][0];

    // --- gather: 32x35 output elems across 256 threads, coalesced ---
    float*       o    = out + (size_t)gw * NSAMPLE * OUTC;
    const float* prow = points + (size_t)b * NPTS * CHANC;
    for (int e = tid; e < NSAMPLE * OUTC; e += 256) {
        const int s = e / OUTC;
        const int c = e - s * OUTC;
        int j;
        if (s < kk) {
            const int rr  = (int)(s >= o1) + (int)(s >= o2) + (int)(s >= o3);
            const int off = (rr == 0) ? 0 : (rr == 1) ? o1 : (rr == 2) ? o2 : o3;
            j = qidx[rr][s - off];
        } else {
            j = firstIdx;
        }
        float v;
        if (c < 3) {
            const float cc = (c == 0) ? cx : (c == 1) ? cy : cz;
            v = bx[j * 3 + c] - cc;
        } else {
            v = prow[j * CHANC + (c - 3)];
        }
        o[e] = v;   // consecutive lanes -> consecutive addresses (coalesced)
    }
}

// ---------------------------------------------------------------------------
extern "C" void kernel_launch(void* const* d_in, const int* in_sizes, int n_in,
                              void* d_out, int out_size, void* d_ws, size_t ws_size,
                              hipStream_t stream) {
    const float* xyz    = (const float*)d_in[0];   // (8, 8192, 3)  fp32
    const float* points = (const float*)d_in[1];   // (8, 8192, 32) fp32
    float* new_xyz    = (float*)d_out;                         // (8,1024,3)
    float* new_points = new_xyz + (size_t)BATCH * NPOINT * 3;  // (8,1024,32,35)

    fps_kernel<<<BATCH, 512, 0, stream>>>(xyz, new_xyz);
    ballgroup_kernel<<<BATCH * NPOINT, 256, 0, stream>>>(xyz, points, new_xyz, new_points);
}